// Round 4
// baseline (333.864 us; speedup 1.0000x reference)
//
#include <hip/hip_runtime.h>
#include <float.h>

#define B_ 16
#define D_ 64
#define L_ 8192
#define K_ 512
#define NBLOCKS 512
#define TILES_PER_BLOCK 4     // 2048 tiles / 512 blocks -> 2 blocks/CU
#define EPS 0.0625f

typedef __attribute__((ext_vector_type(8))) short short8;
typedef __attribute__((ext_vector_type(4))) float f32x4;

__device__ __forceinline__ unsigned short bf16_rne(float x) {
    unsigned u = __float_as_uint(x);
    return (unsigned short)((u + 0x7fffu + ((u >> 16) & 1u)) >> 16);
}

// 512 threads = 8 waves. Wave w: codes w*64..w*64+63 (B-frags resident in regs),
// all 64 tokens (4 row-blocks). C-frag: col=lane&15, row=(lane>>4)*4+reg.
__global__ __launch_bounds__(512, 4)
void vq_mfma_kernel(const float* __restrict__ X, const float* __restrict__ E,
                    float* __restrict__ out_emb, float* __restrict__ out_idx)
{
    __shared__ __align__(16) short xAhi[4096];   // A-frags hi, frag-linear
    __shared__ __align__(16) short xAlo[4096];
    __shared__ float xT[64][65];                 // fp32 x, [d][token]
    __shared__ float esq_s[K_];
    __shared__ float xsq_s[64];
    __shared__ float redm1[8][64];
    __shared__ float redm2[8][64];
    __shared__ int   redk1[8][64];
    __shared__ unsigned long long red64_w[8];
    __shared__ int bestk_s[64];
    __shared__ int flag_s[64];
    __shared__ int nflag_s;

    const int tid  = threadIdx.x;
    const int lane = tid & 63;
    const int wave = tid >> 6;
    const int lo4  = lane & 15;
    const int hi4  = lane >> 4;

    // ---- esq: np sequential axis-0 (round square, ordered adds), prefetched
    {
        float s = 0.f;
        #pragma unroll
        for (int c = 0; c < 4; ++c) {
            float v[16];
            #pragma unroll
            for (int m = 0; m < 16; ++m) v[m] = E[(c * 16 + m) * K_ + tid];
            #pragma unroll
            for (int m = 0; m < 16; ++m) {
                float sq = v[m] * v[m];
                asm volatile("" : "+v"(sq));     // np rounds the square first
                s = s + sq;
            }
        }
        esq_s[tid] = s;
    }

    // ---- resident B-frags (codebook hi/lo bf16); k-map cancels vs A ----
    short8 Bhi[4][2], Blo[4][2];
    #pragma unroll
    for (int q = 0; q < 4; ++q) {
        int code = (wave * 4 + q) * 16 + lo4;
        #pragma unroll
        for (int s = 0; s < 2; ++s) {
            short8 h, l;
            #pragma unroll
            for (int j = 0; j < 8; ++j) {
                int d = s * 32 + hi4 * 8 + j;
                float v = E[d * K_ + code];
                unsigned short hb = bf16_rne(v);
                float hf = __uint_as_float((unsigned)hb << 16);
                h[j] = (short)hb;
                l[j] = (short)bf16_rne(v - hf);
            }
            Bhi[q][s] = h;
            Blo[q][s] = l;
        }
    }

    for (int t = 0; t < TILES_PER_BLOCK; ++t) {
        int tile = blockIdx.x * TILES_PER_BLOCK + t;
        int b  = tile >> 7;
        int l0 = (tile & 127) << 6;

        __syncthreads();                                         // B1

        // ---- stage x: fp32 xT + hi/lo bf16 A-frags ----
        {
            const float* xb = X + ((size_t)(b * 64 + wave * 8)) * L_ + l0 + lane;
            float xv[8];
            #pragma unroll
            for (int r = 0; r < 8; ++r) xv[r] = xb[(size_t)r * L_];
            #pragma unroll
            for (int r = 0; r < 8; ++r) xT[wave * 8 + r][lane] = xv[r];
            short8 h8, l8;
            #pragma unroll
            for (int r = 0; r < 8; ++r) {
                unsigned short hb = bf16_rne(xv[r]);
                float hf = __uint_as_float((unsigned)hb << 16);
                h8[r] = (short)hb;
                l8[r] = (short)bf16_rne(xv[r] - hf);
            }
            int s  = wave >> 2, g = wave & 3;
            int tb = lane >> 4, row = lane & 15;
            int unit = (tb * 2 + s) * 64 + g * 16 + row;
            ((short8*)xAhi)[unit] = h8;
            ((short8*)xAlo)[unit] = l8;
        }
        if (tid == 0) nflag_s = 0;
        __syncthreads();                                         // B2

        // ---- xsq (np pairwise-8) by wave 0; other waves proceed to MFMA ----
        if (tid < 64) {
            float r8[8];
            #pragma unroll
            for (int j = 0; j < 8; ++j) {
                float v = xT[j][tid];
                float sq = v * v;
                asm volatile("" : "+v"(sq));
                r8[j] = sq;
            }
            #pragma unroll
            for (int m = 1; m < 8; ++m)
                #pragma unroll
                for (int j = 0; j < 8; ++j) {
                    float v = xT[m * 8 + j][tid];
                    float sq = v * v;
                    asm volatile("" : "+v"(sq));
                    r8[j] = r8[j] + sq;
                }
            xsq_s[tid] = ((r8[0] + r8[1]) + (r8[2] + r8[3])) +
                         ((r8[4] + r8[5]) + (r8[6] + r8[7]));
        }

        // ---- MFMA: 4 row-blocks x 4 col-blocks x 6 (K=192 hi/lo) ----
        f32x4 acc[4][4];
        #pragma unroll
        for (int tb = 0; tb < 4; ++tb) {
            short8 ah0 = ((const short8*)xAhi)[(tb * 2 + 0) * 64 + lane];
            short8 ah1 = ((const short8*)xAhi)[(tb * 2 + 1) * 64 + lane];
            short8 al0 = ((const short8*)xAlo)[(tb * 2 + 0) * 64 + lane];
            short8 al1 = ((const short8*)xAlo)[(tb * 2 + 1) * 64 + lane];
            #pragma unroll
            for (int q = 0; q < 4; ++q) {
                f32x4 c = {0.f, 0.f, 0.f, 0.f};
                c = __builtin_amdgcn_mfma_f32_16x16x32_bf16(ah0, Bhi[q][0], c, 0, 0, 0);
                c = __builtin_amdgcn_mfma_f32_16x16x32_bf16(ah1, Bhi[q][1], c, 0, 0, 0);
                c = __builtin_amdgcn_mfma_f32_16x16x32_bf16(ah0, Blo[q][0], c, 0, 0, 0);
                c = __builtin_amdgcn_mfma_f32_16x16x32_bf16(ah1, Blo[q][1], c, 0, 0, 0);
                c = __builtin_amdgcn_mfma_f32_16x16x32_bf16(al0, Bhi[q][0], c, 0, 0, 0);
                c = __builtin_amdgcn_mfma_f32_16x16x32_bf16(al1, Bhi[q][1], c, 0, 0, 0);
                acc[tb][q] = c;
            }
        }
        __syncthreads();                                         // B3 (xsq ready)

        // ---- scores + per-token (m1,k1,m2) triple, single shfl tree ----
        float es_q[4];
        #pragma unroll
        for (int q = 0; q < 4; ++q) es_q[q] = esq_s[(wave * 4 + q) * 16 + lo4];

        float m1[4][4], m2[4][4];
        int   k1[4][4];
        #pragma unroll
        for (int tb = 0; tb < 4; ++tb)
            #pragma unroll
            for (int r = 0; r < 4; ++r) {
                float xs = xsq_s[tb * 16 + hi4 * 4 + r];
                float a = FLT_MAX, bsec = FLT_MAX;
                int   ka = 0x7FFFFFFF;
                #pragma unroll
                for (int q = 0; q < 4; ++q) {
                    float sc = (xs - 2.0f * acc[tb][q][r]) + es_q[q];
                    int   cd = (wave * 4 + q) * 16 + lo4;
                    if (sc < a) { bsec = a; a = sc; ka = cd; }
                    else        { bsec = fminf(bsec, sc); }
                }
                m1[tb][r] = a; k1[tb][r] = ka; m2[tb][r] = bsec;
            }
        #pragma unroll
        for (int off = 1; off < 16; off <<= 1)
            #pragma unroll
            for (int tb = 0; tb < 4; ++tb)
                #pragma unroll
                for (int r = 0; r < 4; ++r) {
                    float ov = __shfl_xor(m1[tb][r], off, 64);
                    int   ok = __shfl_xor(k1[tb][r], off, 64);
                    float o2 = __shfl_xor(m2[tb][r], off, 64);
                    float n2 = fminf(fminf(m2[tb][r], o2), fmaxf(m1[tb][r], ov));
                    if (ov < m1[tb][r] || (ov == m1[tb][r] && ok < k1[tb][r])) {
                        m1[tb][r] = ov; k1[tb][r] = ok;
                    }
                    m2[tb][r] = n2;
                }
        if (lo4 == 0)
            #pragma unroll
            for (int tb = 0; tb < 4; ++tb)
                #pragma unroll
                for (int r = 0; r < 4; ++r) {
                    int token = tb * 16 + hi4 * 4 + r;
                    redm1[wave][token] = m1[tb][r];
                    redk1[wave][token] = k1[tb][r];
                    redm2[wave][token] = m2[tb][r];
                }
        __syncthreads();                                         // B4

        // ---- combine 8 waves; decide or flag ----
        if (tid < 64) {
            float a = redm1[0][tid], bsec = redm2[0][tid];
            int   ka = redk1[0][tid];
            #pragma unroll
            for (int w = 1; w < 8; ++w) {
                float ov = redm1[w][tid], o2 = redm2[w][tid];
                int   ok = redk1[w][tid];
                float n2 = fminf(fminf(bsec, o2), fmaxf(a, ov));
                if (ov < a || (ov == a && ok < ka)) { a = ov; ka = ok; }
                bsec = n2;
            }
            if (bsec <= a + EPS) {               // near-tie -> exact recompute
                int p = atomicAdd(&nflag_s, 1);
                flag_s[p] = tid;
            } else {
                bestk_s[tid] = ka;               // unique winner == np argmin
            }
        }
        __syncthreads();                                         // B5

        // ---- rare exact pass: block-coop, thread = code, np-bitexact chain
        int nf = nflag_s;
        for (int f = 0; f < nf; ++f) {
            int token = flag_s[f];
            float xs = xsq_s[token];
            float es = esq_s[tid];
            float dot = 0.f;
            #pragma unroll
            for (int c = 0; c < 4; ++c) {
                float ev[16], xv[16];
                #pragma unroll
                for (int m = 0; m < 16; ++m) ev[m] = E[(c * 16 + m) * K_ + tid];
                #pragma unroll
                for (int m = 0; m < 16; ++m) xv[m] = xT[c * 16 + m][token];
                #pragma unroll
                for (int m = 0; m < 16; ++m) dot = fmaf(xv[m], ev[m], dot);
            }
            float ex = (xs - 2.0f * dot) + es;
            unsigned long long pk =
                ((unsigned long long)__float_as_uint(ex) << 32) | (unsigned)tid;
            #pragma unroll
            for (int off = 1; off < 64; off <<= 1) {
                unsigned long long o = __shfl_xor(pk, off, 64);
                if (o < pk) pk = o;
            }
            if (lane == 0) red64_w[wave] = pk;
            __syncthreads();
            if (tid == 0) {
                unsigned long long m = red64_w[0];
                #pragma unroll
                for (int w = 1; w < 8; ++w) {
                    unsigned long long o = red64_w[w];
                    if (o < m) m = o;
                }
                bestk_s[token] = (int)(unsigned)(m & 0xFFFFFFFFULL);
            }
            __syncthreads();
        }

        // ---- epilogue: gather exact fp32 codebook rows + write ----
        {
            int qd = tid & 15, dg = tid >> 4;
            int i4 = qd * 4;
            int k0 = bestk_s[i4], kk1 = bestk_s[i4 + 1];
            int k2 = bestk_s[i4 + 2], k3 = bestk_s[i4 + 3];
            #pragma unroll
            for (int h = 0; h < 2; ++h) {
                int d = dg + h * 32;
                float4 v;
                v.x = E[d * K_ + k0];  v.y = E[d * K_ + kk1];
                v.z = E[d * K_ + k2];  v.w = E[d * K_ + k3];
                *reinterpret_cast<float4*>(out_emb + ((size_t)(b * 64 + d)) * L_ + l0 + i4) = v;
            }
        }
        if (tid < 64)
            out_idx[(size_t)b * L_ + l0 + tid] = (float)bestk_s[tid];
    }
}

extern "C" void kernel_launch(void* const* d_in, const int* in_sizes, int n_in,
                              void* d_out, int out_size, void* d_ws, size_t ws_size,
                              hipStream_t stream) {
    const float* X = (const float*)d_in[0];   // (B, D, L) fp32
    const float* E = (const float*)d_in[1];   // (D, K) fp32
    float* out     = (float*)d_out;
    float* out_emb = out;
    float* out_idx = out + (size_t)B_ * D_ * L_;
    vq_mfma_kernel<<<NBLOCKS, 512, 0, stream>>>(X, E, out_emb, out_idx);
}

// Round 5
// 239.674 us; speedup vs baseline: 1.3930x; 1.3930x over previous
//
#include <hip/hip_runtime.h>
#include <float.h>

#define B_ 16
#define D_ 64
#define L_ 8192
#define K_ 512
#define NBLOCKS 512
#define TILES_PER_BLOCK 4     // 2048 tiles / 512 blocks -> 2 blocks/CU
#define EPS 0.0625f

typedef __attribute__((ext_vector_type(8))) short short8;
typedef __attribute__((ext_vector_type(4))) float f32x4;

__device__ __forceinline__ unsigned short bf16_rne(float x) {
    unsigned u = __float_as_uint(x);
    return (unsigned short)((u + 0x7fffu + ((u >> 16) & 1u)) >> 16);
}

__device__ __forceinline__ unsigned f32_sortable(float x) {
    unsigned u = __float_as_uint(x);
    return u ^ (((int)u >> 31) | 0x80000000u);   // ascending uint == ascending float
}

// 512 threads = 8 waves. Wave w: codes w*64..w*64+63 (B-frags resident in regs),
// all 64 tokens (4 row-blocks). C-frag: col=lane&15, row=(lane>>4)*4+reg.
// NOTE launch_bounds 2nd arg is min BLOCKS/CU (CUDA semantics): 2 blocks x 8
// waves = 16 waves/CU -> VGPR cap 128. (512,4) forced cap 64 -> 800 MB spill.
__global__ __launch_bounds__(512, 2)
void vq_mfma_kernel(const float* __restrict__ X, const float* __restrict__ E,
                    float* __restrict__ out_emb, float* __restrict__ out_idx)
{
    __shared__ __align__(16) short xAhi[4096];   // A-frags hi, frag-linear
    __shared__ __align__(16) short xAlo[4096];
    __shared__ float xT[64][65];                 // fp32 x, [d][token]
    __shared__ float esq_s[K_];
    __shared__ float xsq_s[64];
    __shared__ float redm1[8][64];
    __shared__ float redm2[8][64];
    __shared__ int   redk1[8][64];
    __shared__ unsigned long long red64_w[8];
    __shared__ int bestk_s[64];
    __shared__ int flag_s[64];
    __shared__ int nflag_s;

    const int tid  = threadIdx.x;
    const int lane = tid & 63;
    const int wave = tid >> 6;
    const int lo4  = lane & 15;
    const int hi4  = lane >> 4;

    // ---- esq: np sequential axis-0 (round square, ordered adds), prefetched
    {
        float s = 0.f;
        #pragma unroll
        for (int c = 0; c < 4; ++c) {
            float v[16];
            #pragma unroll
            for (int m = 0; m < 16; ++m) v[m] = E[(c * 16 + m) * K_ + tid];
            #pragma unroll
            for (int m = 0; m < 16; ++m) {
                float sq = v[m] * v[m];
                asm volatile("" : "+v"(sq));     // np rounds the square first
                s = s + sq;
            }
        }
        esq_s[tid] = s;
    }

    // ---- resident B-frags (codebook hi/lo bf16); k-map cancels vs A ----
    short8 Bhi[4][2], Blo[4][2];
    #pragma unroll
    for (int q = 0; q < 4; ++q) {
        int code = (wave * 4 + q) * 16 + lo4;
        #pragma unroll
        for (int s = 0; s < 2; ++s) {
            short8 h, l;
            #pragma unroll
            for (int j = 0; j < 8; ++j) {
                int d = s * 32 + hi4 * 8 + j;
                float v = E[d * K_ + code];
                unsigned short hb = bf16_rne(v);
                float hf = __uint_as_float((unsigned)hb << 16);
                h[j] = (short)hb;
                l[j] = (short)bf16_rne(v - hf);
            }
            Bhi[q][s] = h;
            Blo[q][s] = l;
        }
    }

    for (int t = 0; t < TILES_PER_BLOCK; ++t) {
        int tile = blockIdx.x * TILES_PER_BLOCK + t;
        int b  = tile >> 7;
        int l0 = (tile & 127) << 6;

        __syncthreads();                                         // B1

        // ---- stage x: fp32 xT + hi/lo bf16 A-frags ----
        {
            const float* xb = X + ((size_t)(b * 64 + wave * 8)) * L_ + l0 + lane;
            float xv[8];
            #pragma unroll
            for (int r = 0; r < 8; ++r) xv[r] = xb[(size_t)r * L_];
            #pragma unroll
            for (int r = 0; r < 8; ++r) xT[wave * 8 + r][lane] = xv[r];
            short8 h8, l8;
            #pragma unroll
            for (int r = 0; r < 8; ++r) {
                unsigned short hb = bf16_rne(xv[r]);
                float hf = __uint_as_float((unsigned)hb << 16);
                h8[r] = (short)hb;
                l8[r] = (short)bf16_rne(xv[r] - hf);
            }
            int s  = wave >> 2, g = wave & 3;
            int tb = lane >> 4, row = lane & 15;
            int unit = (tb * 2 + s) * 64 + g * 16 + row;
            ((short8*)xAhi)[unit] = h8;
            ((short8*)xAlo)[unit] = l8;
        }
        if (tid == 0) nflag_s = 0;
        __syncthreads();                                         // B2

        // ---- xsq (np pairwise-8) by wave 0; other waves proceed to MFMA ----
        if (tid < 64) {
            float r8[8];
            #pragma unroll
            for (int j = 0; j < 8; ++j) {
                float v = xT[j][tid];
                float sq = v * v;
                asm volatile("" : "+v"(sq));
                r8[j] = sq;
            }
            #pragma unroll
            for (int m = 1; m < 8; ++m)
                #pragma unroll
                for (int j = 0; j < 8; ++j) {
                    float v = xT[m * 8 + j][tid];
                    float sq = v * v;
                    asm volatile("" : "+v"(sq));
                    r8[j] = r8[j] + sq;
                }
            xsq_s[tid] = ((r8[0] + r8[1]) + (r8[2] + r8[3])) +
                         ((r8[4] + r8[5]) + (r8[6] + r8[7]));
        }

        // ---- MFMA: 4 row-blocks x 4 col-blocks x 6 (K=192 hi/lo) ----
        f32x4 acc[4][4];
        #pragma unroll
        for (int tb = 0; tb < 4; ++tb) {
            short8 ah0 = ((const short8*)xAhi)[(tb * 2 + 0) * 64 + lane];
            short8 ah1 = ((const short8*)xAhi)[(tb * 2 + 1) * 64 + lane];
            short8 al0 = ((const short8*)xAlo)[(tb * 2 + 0) * 64 + lane];
            short8 al1 = ((const short8*)xAlo)[(tb * 2 + 1) * 64 + lane];
            #pragma unroll
            for (int q = 0; q < 4; ++q) {
                f32x4 c = {0.f, 0.f, 0.f, 0.f};
                c = __builtin_amdgcn_mfma_f32_16x16x32_bf16(ah0, Bhi[q][0], c, 0, 0, 0);
                c = __builtin_amdgcn_mfma_f32_16x16x32_bf16(ah1, Bhi[q][1], c, 0, 0, 0);
                c = __builtin_amdgcn_mfma_f32_16x16x32_bf16(ah0, Blo[q][0], c, 0, 0, 0);
                c = __builtin_amdgcn_mfma_f32_16x16x32_bf16(ah1, Blo[q][1], c, 0, 0, 0);
                c = __builtin_amdgcn_mfma_f32_16x16x32_bf16(al0, Bhi[q][0], c, 0, 0, 0);
                c = __builtin_amdgcn_mfma_f32_16x16x32_bf16(al1, Bhi[q][1], c, 0, 0, 0);
                acc[tb][q] = c;
            }
        }
        __syncthreads();                                         // B3 (xsq ready)

        // ---- scores + per-token (m1,k1,m2) triple, single shfl tree ----
        float es_q[4];
        #pragma unroll
        for (int q = 0; q < 4; ++q) es_q[q] = esq_s[(wave * 4 + q) * 16 + lo4];

        float m1[4][4], m2[4][4];
        int   k1[4][4];
        #pragma unroll
        for (int tb = 0; tb < 4; ++tb)
            #pragma unroll
            for (int r = 0; r < 4; ++r) {
                float xs = xsq_s[tb * 16 + hi4 * 4 + r];
                float a = FLT_MAX, bsec = FLT_MAX;
                int   ka = 0x7FFFFFFF;
                #pragma unroll
                for (int q = 0; q < 4; ++q) {
                    float sc = (xs - 2.0f * acc[tb][q][r]) + es_q[q];
                    int   cd = (wave * 4 + q) * 16 + lo4;
                    if (sc < a) { bsec = a; a = sc; ka = cd; }
                    else        { bsec = fminf(bsec, sc); }
                }
                m1[tb][r] = a; k1[tb][r] = ka; m2[tb][r] = bsec;
            }
        #pragma unroll
        for (int off = 1; off < 16; off <<= 1)
            #pragma unroll
            for (int tb = 0; tb < 4; ++tb)
                #pragma unroll
                for (int r = 0; r < 4; ++r) {
                    float ov = __shfl_xor(m1[tb][r], off, 64);
                    int   ok = __shfl_xor(k1[tb][r], off, 64);
                    float o2 = __shfl_xor(m2[tb][r], off, 64);
                    float n2 = fminf(fminf(m2[tb][r], o2), fmaxf(m1[tb][r], ov));
                    if (ov < m1[tb][r] || (ov == m1[tb][r] && ok < k1[tb][r])) {
                        m1[tb][r] = ov; k1[tb][r] = ok;
                    }
                    m2[tb][r] = n2;
                }
        if (lo4 == 0)
            #pragma unroll
            for (int tb = 0; tb < 4; ++tb)
                #pragma unroll
                for (int r = 0; r < 4; ++r) {
                    int token = tb * 16 + hi4 * 4 + r;
                    redm1[wave][token] = m1[tb][r];
                    redk1[wave][token] = k1[tb][r];
                    redm2[wave][token] = m2[tb][r];
                }
        __syncthreads();                                         // B4

        // ---- combine 8 waves; decide or flag ----
        if (tid < 64) {
            float a = redm1[0][tid], bsec = redm2[0][tid];
            int   ka = redk1[0][tid];
            #pragma unroll
            for (int w = 1; w < 8; ++w) {
                float ov = redm1[w][tid], o2 = redm2[w][tid];
                int   ok = redk1[w][tid];
                float n2 = fminf(fminf(bsec, o2), fmaxf(a, ov));
                if (ov < a || (ov == a && ok < ka)) { a = ov; ka = ok; }
                bsec = n2;
            }
            if (bsec <= a + EPS) {               // near-tie -> exact recompute
                int p = atomicAdd(&nflag_s, 1);
                flag_s[p] = tid;
            } else {
                bestk_s[tid] = ka;               // unique winner == np argmin
            }
        }
        __syncthreads();                                         // B5

        // ---- rare exact pass: block-coop, thread = code, np-bitexact chain
        int nf = nflag_s;
        for (int f = 0; f < nf; ++f) {
            int token = flag_s[f];
            float xs = xsq_s[token];
            float es = esq_s[tid];
            float dot = 0.f;
            #pragma unroll
            for (int c = 0; c < 4; ++c) {
                float ev[16], xv[16];
                #pragma unroll
                for (int m = 0; m < 16; ++m) ev[m] = E[(c * 16 + m) * K_ + tid];
                #pragma unroll
                for (int m = 0; m < 16; ++m) xv[m] = xT[c * 16 + m][token];
                #pragma unroll
                for (int m = 0; m < 16; ++m) dot = fmaf(xv[m], ev[m], dot);
            }
            float ex = (xs - 2.0f * dot) + es;
            unsigned long long pk =
                ((unsigned long long)f32_sortable(ex) << 32) | (unsigned)tid;
            #pragma unroll
            for (int off = 1; off < 64; off <<= 1) {
                unsigned long long o = __shfl_xor(pk, off, 64);
                if (o < pk) pk = o;
            }
            if (lane == 0) red64_w[wave] = pk;
            __syncthreads();
            if (tid == 0) {
                unsigned long long m = red64_w[0];
                #pragma unroll
                for (int w = 1; w < 8; ++w) {
                    unsigned long long o = red64_w[w];
                    if (o < m) m = o;
                }
                bestk_s[token] = (int)(unsigned)(m & 0xFFFFFFFFULL);
            }
            __syncthreads();
        }

        // ---- epilogue: gather exact fp32 codebook rows + write ----
        {
            int qd = tid & 15, dg = tid >> 4;
            int i4 = qd * 4;
            int k0 = bestk_s[i4], kk1 = bestk_s[i4 + 1];
            int k2 = bestk_s[i4 + 2], k3 = bestk_s[i4 + 3];
            #pragma unroll
            for (int h = 0; h < 2; ++h) {
                int d = dg + h * 32;
                float4 v;
                v.x = E[d * K_ + k0];  v.y = E[d * K_ + kk1];
                v.z = E[d * K_ + k2];  v.w = E[d * K_ + k3];
                *reinterpret_cast<float4*>(out_emb + ((size_t)(b * 64 + d)) * L_ + l0 + i4) = v;
            }
        }
        if (tid < 64)
            out_idx[(size_t)b * L_ + l0 + tid] = (float)bestk_s[tid];
    }
}

extern "C" void kernel_launch(void* const* d_in, const int* in_sizes, int n_in,
                              void* d_out, int out_size, void* d_ws, size_t ws_size,
                              hipStream_t stream) {
    const float* X = (const float*)d_in[0];   // (B, D, L) fp32
    const float* E = (const float*)d_in[1];   // (D, K) fp32
    float* out     = (float*)d_out;
    float* out_emb = out;
    float* out_idx = out + (size_t)B_ * D_ * L_;
    vq_mfma_kernel<<<NBLOCKS, 512, 0, stream>>>(X, E, out_emb, out_idx);
}

// Round 6
// 191.359 us; speedup vs baseline: 1.7447x; 1.2525x over previous
//
#include <hip/hip_runtime.h>
#include <float.h>

#define B_ 16
#define D_ 64
#define L_ 8192
#define K_ 512
#define NBLOCKS 512
#define TILES_PER_BLOCK 4     // 2048 tiles / 512 blocks -> 2 blocks/CU
#define EPS 0.25f             // ~15 sigma of fp16-dot score error; exact pass covers ties

typedef __attribute__((ext_vector_type(8))) short    short8;
typedef __attribute__((ext_vector_type(8))) _Float16 half8;
typedef __attribute__((ext_vector_type(4))) float    f32x4;

__device__ __forceinline__ unsigned f32_sortable(float x) {
    unsigned u = __float_as_uint(x);
    return u ^ (((int)u >> 31) | 0x80000000u);   // ascending uint == ascending float
}

// 512 threads = 8 waves. Wave w: codes w*64..w*64+63 (fp16 B-frags resident,
// 32 VGPRs), all 64 tokens (4 row-blocks, consumed one at a time).
// C-frag: token = tb*16 + (lane>>4)*4 + reg, code = colblk*16 + (lane&15).
// launch_bounds 2nd arg is min BLOCKS/CU (CUDA semantics): (512,4) forced a
// 64-VGPR cap -> 800 MB spill (r4); (512,2) caps at 128.
__global__ __launch_bounds__(512, 2)
void vq_mfma_kernel(const float* __restrict__ X, const float* __restrict__ E,
                    float* __restrict__ out_emb, float* __restrict__ out_idx)
{
    __shared__ __align__(16) short xAh[4096];    // fp16 A-frags, frag-linear, 8 KB
    __shared__ float xT[64][65];                 // fp32 x, [d][token]
    __shared__ float esq_s[K_];
    __shared__ float xsq_s[64];
    __shared__ float redm1[8][64];
    __shared__ float redm2[8][64];
    __shared__ int   redk1[8][64];
    __shared__ unsigned long long red64_w[8];
    __shared__ int bestk_s[64];
    __shared__ int flag_s[64];
    __shared__ int nflag_s;

    const int tid  = threadIdx.x;
    const int lane = tid & 63;
    const int wave = tid >> 6;
    const int lo4  = lane & 15;
    const int hi4  = lane >> 4;

    // ---- esq: np sequential axis-0 (round square, ordered adds), prefetched
    {
        float s = 0.f;
        #pragma unroll
        for (int c = 0; c < 4; ++c) {
            float v[16];
            #pragma unroll
            for (int m = 0; m < 16; ++m) v[m] = E[(c * 16 + m) * K_ + tid];
            #pragma unroll
            for (int m = 0; m < 16; ++m) {
                float sq = v[m] * v[m];
                asm volatile("" : "+v"(sq));     // np rounds the square first
                s = s + sq;
            }
        }
        esq_s[tid] = s;
    }

    // ---- resident fp16 B-frags (32 VGPRs); k-map permutation cancels vs A --
    half8 Bh[4][2];
    #pragma unroll
    for (int q = 0; q < 4; ++q) {
        int code = (wave * 4 + q) * 16 + lo4;
        #pragma unroll
        for (int s = 0; s < 2; ++s) {
            half8 h;
            #pragma unroll
            for (int j = 0; j < 8; ++j) {
                int d = s * 32 + hi4 * 8 + j;
                h[j] = (_Float16)E[d * K_ + code];   // v_cvt_f16_f32, RNE
            }
            Bh[q][s] = h;
        }
    }

    for (int t = 0; t < TILES_PER_BLOCK; ++t) {
        int tile = blockIdx.x * TILES_PER_BLOCK + t;
        int b  = tile >> 7;
        int l0 = (tile & 127) << 6;

        __syncthreads();                                         // B1

        // ---- stage x: fp32 xT + fp16 A-frags ----
        {
            const float* xb = X + ((size_t)(b * 64 + wave * 8)) * L_ + l0 + lane;
            float xv[8];
            #pragma unroll
            for (int r = 0; r < 8; ++r) xv[r] = xb[(size_t)r * L_];
            #pragma unroll
            for (int r = 0; r < 8; ++r) xT[wave * 8 + r][lane] = xv[r];
            half8 h8;
            #pragma unroll
            for (int r = 0; r < 8; ++r) h8[r] = (_Float16)xv[r];
            int s  = wave >> 2, g = wave & 3;
            int tb = lane >> 4, row = lane & 15;
            ((half8*)xAh)[(tb * 2 + s) * 64 + g * 16 + row] = h8;
        }
        if (tid == 0) nflag_s = 0;
        __syncthreads();                                         // B2

        // ---- xsq (np pairwise-8) by wave 0 ----
        if (tid < 64) {
            float r8[8];
            #pragma unroll
            for (int j = 0; j < 8; ++j) {
                float v = xT[j][tid];
                float sq = v * v;
                asm volatile("" : "+v"(sq));
                r8[j] = sq;
            }
            #pragma unroll
            for (int m = 1; m < 8; ++m)
                #pragma unroll
                for (int j = 0; j < 8; ++j) {
                    float v = xT[m * 8 + j][tid];
                    float sq = v * v;
                    asm volatile("" : "+v"(sq));
                    r8[j] = r8[j] + sq;
                }
            xsq_s[tid] = ((r8[0] + r8[1]) + (r8[2] + r8[3])) +
                         ((r8[4] + r8[5]) + (r8[6] + r8[7]));
        }
        __syncthreads();                                         // B3 (xsq ready)

        float es_q[4];
        #pragma unroll
        for (int q = 0; q < 4; ++q) es_q[q] = esq_s[(wave * 4 + q) * 16 + lo4];

        // ---- per row-block: 8 MFMA -> scores -> triple -> shfl tree -> LDS
        #pragma unroll
        for (int tb = 0; tb < 4; ++tb) {
            half8 ah0 = ((const half8*)xAh)[(tb * 2 + 0) * 64 + lane];
            half8 ah1 = ((const half8*)xAh)[(tb * 2 + 1) * 64 + lane];
            f32x4 c[4];
            #pragma unroll
            for (int q = 0; q < 4; ++q) {
                f32x4 z = {0.f, 0.f, 0.f, 0.f};
                z = __builtin_amdgcn_mfma_f32_16x16x32_f16(ah0, Bh[q][0], z, 0, 0, 0);
                z = __builtin_amdgcn_mfma_f32_16x16x32_f16(ah1, Bh[q][1], z, 0, 0, 0);
                c[q] = z;
            }
            float m1[4], m2[4];
            int   k1[4];
            #pragma unroll
            for (int r = 0; r < 4; ++r) {
                float xs = xsq_s[tb * 16 + hi4 * 4 + r];
                float a = FLT_MAX, bsec = FLT_MAX;
                int   ka = 0x7FFFFFFF;
                #pragma unroll
                for (int q = 0; q < 4; ++q) {
                    float sc = (xs - 2.0f * c[q][r]) + es_q[q];
                    int   cd = (wave * 4 + q) * 16 + lo4;
                    if (sc < a) { bsec = a; a = sc; ka = cd; }
                    else        { bsec = fminf(bsec, sc); }
                }
                m1[r] = a; k1[r] = ka; m2[r] = bsec;
            }
            #pragma unroll
            for (int off = 1; off < 16; off <<= 1)
                #pragma unroll
                for (int r = 0; r < 4; ++r) {
                    float ov = __shfl_xor(m1[r], off, 64);
                    int   ok = __shfl_xor(k1[r], off, 64);
                    float o2 = __shfl_xor(m2[r], off, 64);
                    float n2 = fminf(fminf(m2[r], o2), fmaxf(m1[r], ov));
                    if (ov < m1[r] || (ov == m1[r] && ok < k1[r])) {
                        m1[r] = ov; k1[r] = ok;
                    }
                    m2[r] = n2;
                }
            if (lo4 == 0)
                #pragma unroll
                for (int r = 0; r < 4; ++r) {
                    int token = tb * 16 + hi4 * 4 + r;
                    redm1[wave][token] = m1[r];
                    redk1[wave][token] = k1[r];
                    redm2[wave][token] = m2[r];
                }
        }
        __syncthreads();                                         // B4

        // ---- combine 8 waves; decide or flag ----
        if (tid < 64) {
            float a = redm1[0][tid], bsec = redm2[0][tid];
            int   ka = redk1[0][tid];
            #pragma unroll
            for (int w = 1; w < 8; ++w) {
                float ov = redm1[w][tid], o2 = redm2[w][tid];
                int   ok = redk1[w][tid];
                float n2 = fminf(fminf(bsec, o2), fmaxf(a, ov));
                if (ov < a || (ov == a && ok < ka)) { a = ov; ka = ok; }
                bsec = n2;
            }
            if (bsec <= a + EPS) {               // near-tie -> exact recompute
                int p = atomicAdd(&nflag_s, 1);
                flag_s[p] = tid;
            } else {
                bestk_s[tid] = ka;               // unique winner == np argmin
            }
        }
        __syncthreads();                                         // B5

        // ---- rare exact pass: block-coop, thread = code, np-bitexact chain
        int nf = nflag_s;
        for (int f = 0; f < nf; ++f) {
            int token = flag_s[f];
            float xs = xsq_s[token];
            float es = esq_s[tid];
            float dot = 0.f;
            #pragma unroll
            for (int c4 = 0; c4 < 4; ++c4) {
                float ev[16], xv[16];
                #pragma unroll
                for (int m = 0; m < 16; ++m) ev[m] = E[(c4 * 16 + m) * K_ + tid];
                #pragma unroll
                for (int m = 0; m < 16; ++m) xv[m] = xT[c4 * 16 + m][token];
                #pragma unroll
                for (int m = 0; m < 16; ++m) dot = fmaf(xv[m], ev[m], dot);
            }
            float ex = (xs - 2.0f * dot) + es;
            unsigned long long pk =
                ((unsigned long long)f32_sortable(ex) << 32) | (unsigned)tid;
            #pragma unroll
            for (int off = 1; off < 64; off <<= 1) {
                unsigned long long o = __shfl_xor(pk, off, 64);
                if (o < pk) pk = o;
            }
            if (lane == 0) red64_w[wave] = pk;
            __syncthreads();
            if (tid == 0) {
                unsigned long long m = red64_w[0];
                #pragma unroll
                for (int w = 1; w < 8; ++w) {
                    unsigned long long o = red64_w[w];
                    if (o < m) m = o;
                }
                bestk_s[token] = (int)(unsigned)(m & 0xFFFFFFFFULL);
            }
            __syncthreads();
        }

        // ---- epilogue: gather exact fp32 codebook rows + write ----
        {
            int qd = tid & 15, dg = tid >> 4;
            int i4 = qd * 4;
            int k0 = bestk_s[i4], kk1 = bestk_s[i4 + 1];
            int k2 = bestk_s[i4 + 2], k3 = bestk_s[i4 + 3];
            #pragma unroll
            for (int h = 0; h < 2; ++h) {
                int d = dg + h * 32;
                float4 v;
                v.x = E[d * K_ + k0];  v.y = E[d * K_ + kk1];
                v.z = E[d * K_ + k2];  v.w = E[d * K_ + k3];
                *reinterpret_cast<float4*>(out_emb + ((size_t)(b * 64 + d)) * L_ + l0 + i4) = v;
            }
        }
        if (tid < 64)
            out_idx[(size_t)b * L_ + l0 + tid] = (float)bestk_s[tid];
    }
}

extern "C" void kernel_launch(void* const* d_in, const int* in_sizes, int n_in,
                              void* d_out, int out_size, void* d_ws, size_t ws_size,
                              hipStream_t stream) {
    const float* X = (const float*)d_in[0];   // (B, D, L) fp32
    const float* E = (const float*)d_in[1];   // (D, K) fp32
    float* out     = (float*)d_out;
    float* out_emb = out;
    float* out_idx = out + (size_t)B_ * D_ * L_;
    vq_mfma_kernel<<<NBLOCKS, 512, 0, stream>>>(X, E, out_emb, out_idx);
}

// Round 9
// 132.407 us; speedup vs baseline: 2.5215x; 1.4452x over previous
//
#include <hip/hip_runtime.h>
#include <float.h>

#define B_ 16
#define D_ 64
#define L_ 8192
#define K_ 512
#define NBLOCKS 512
#define TILES_PER_BLOCK 4     // 2048 tiles / 512 blocks -> 2 blocks/CU
#define EPS 0.0625f           // fp16 score err 6sigma*2 ~= 0.039 < EPS; exact pass covers flags

// r9 = identical resubmit of r7/r8 (container died before bench ran, twice).

typedef __attribute__((ext_vector_type(8))) _Float16 half8;
typedef __attribute__((ext_vector_type(4))) float    f32x4;

__device__ __forceinline__ unsigned f32_sortable(float x) {
    unsigned u = __float_as_uint(x);
    return u ^ (((int)u >> 31) | 0x80000000u);   // ascending uint == ascending float
}

// 512 threads = 8 waves. Wave w: codes w*64..w*64+63 (fp16 B-frags resident, 32
// VGPRs), all 64 tokens (4 row-blocks consumed one at a time).
// C-frag: token = tb*16 + (lane>>4)*4 + reg, code = colblk*16 + (lane&15).
// launch_bounds 2nd arg = min BLOCKS/CU (CUDA semantics): (512,4) forced 64-VGPR
// cap -> 800 MB spill (r4); (512,2) caps at 128.
__global__ __launch_bounds__(512, 2)
void vq_mfma_kernel(const float* __restrict__ X, const float* __restrict__ E,
                    float* __restrict__ out_emb, float* __restrict__ out_idx)
{
    __shared__ __align__(16) short xAh[4096];    // fp16 A-frags, frag-linear, 8 KB
    __shared__ float xT[64][65];                 // fp32 x, [d][token]
    __shared__ float esq_s[K_];
    __shared__ float xsq_s[64];
    __shared__ float redm1[8][65];
    __shared__ float redm2[8][65];
    __shared__ int   redk1[8][65];
    __shared__ int bestk_s[64];
    __shared__ int flag_s[64];
    __shared__ int nflag_s;

    const int tid  = threadIdx.x;
    const int lane = tid & 63;
    const int wave = tid >> 6;
    const int lo4  = lane & 15;
    const int hi4  = lane >> 4;

    // ---- esq: np sequential axis-0 (round square, ordered adds), prefetched
    {
        float s = 0.f;
        #pragma unroll
        for (int c = 0; c < 4; ++c) {
            float v[16];
            #pragma unroll
            for (int m = 0; m < 16; ++m) v[m] = E[(c * 16 + m) * K_ + tid];
            #pragma unroll
            for (int m = 0; m < 16; ++m) {
                float sq = v[m] * v[m];
                asm volatile("" : "+v"(sq));     // np rounds the square first
                s = s + sq;
            }
        }
        esq_s[tid] = s;
    }

    // ---- resident fp16 B-frags (32 VGPRs); k-map permutation cancels vs A --
    half8 Bh[4][2];
    #pragma unroll
    for (int q = 0; q < 4; ++q) {
        int code = (wave * 4 + q) * 16 + lo4;
        #pragma unroll
        for (int s = 0; s < 2; ++s) {
            half8 h;
            #pragma unroll
            for (int j = 0; j < 8; ++j) {
                int d = s * 32 + hi4 * 8 + j;
                h[j] = (_Float16)E[d * K_ + code];   // v_cvt_f16_f32, RNE
            }
            Bh[q][s] = h;
        }
    }

    for (int t = 0; t < TILES_PER_BLOCK; ++t) {
        int tile = blockIdx.x * TILES_PER_BLOCK + t;
        int b  = tile >> 7;
        int l0 = (tile & 127) << 6;

        __syncthreads();                                         // B1

        // ---- stage x: fp32 xT + fp16 A-frags ----
        {
            const float* xb = X + ((size_t)(b * 64 + wave * 8)) * L_ + l0 + lane;
            float xv[8];
            #pragma unroll
            for (int r = 0; r < 8; ++r) xv[r] = xb[(size_t)r * L_];
            #pragma unroll
            for (int r = 0; r < 8; ++r) xT[wave * 8 + r][lane] = xv[r];
            half8 h8;
            #pragma unroll
            for (int r = 0; r < 8; ++r) h8[r] = (_Float16)xv[r];
            int s  = wave >> 2, g = wave & 3;
            int tb = lane >> 4, row = lane & 15;
            ((half8*)xAh)[(tb * 2 + s) * 64 + g * 16 + row] = h8;
        }
        if (tid == 0) nflag_s = 0;
        __syncthreads();                                         // B2

        // ---- xsq: wave-parallel np pairwise-8 (tree shape == np combine) ---
        {
            int tk = wave * 8 + (lane >> 3);
            int j  = lane & 7;
            float r = 0.f;
            #pragma unroll
            for (int m = 0; m < 8; ++m) {
                float v = xT[m * 8 + j][tk];
                float sq = v * v;
                asm volatile("" : "+v"(sq));     // np rounds the square first
                r = r + sq;                      // m ascending: np r[j] order
            }
            r = r + __shfl_xor(r, 1, 64);        // (r0+r1) ...
            r = r + __shfl_xor(r, 2, 64);        // ((r0+r1)+(r2+r3)) ...
            r = r + __shfl_xor(r, 4, 64);        // full pairwise tree
            if (j == 0) xsq_s[tk] = r;
        }
        __syncthreads();                                         // B3

        float es_q[4];
        #pragma unroll
        for (int q = 0; q < 4; ++q) es_q[q] = esq_s[(wave * 4 + q) * 16 + lo4];

        // ---- per row-block: 8 MFMA -> scores -> (m1,k1,m2) -> shfl tree ----
        #pragma unroll
        for (int tb = 0; tb < 4; ++tb) {
            half8 ah0 = ((const half8*)xAh)[(tb * 2 + 0) * 64 + lane];
            half8 ah1 = ((const half8*)xAh)[(tb * 2 + 1) * 64 + lane];
            f32x4 c[4];
            #pragma unroll
            for (int q = 0; q < 4; ++q) {
                f32x4 z = {0.f, 0.f, 0.f, 0.f};
                z = __builtin_amdgcn_mfma_f32_16x16x32_f16(ah0, Bh[q][0], z, 0, 0, 0);
                z = __builtin_amdgcn_mfma_f32_16x16x32_f16(ah1, Bh[q][1], z, 0, 0, 0);
                c[q] = z;
            }
            float m1[4], m2[4];
            int   k1[4];
            #pragma unroll
            for (int r = 0; r < 4; ++r) {
                float xs = xsq_s[tb * 16 + hi4 * 4 + r];
                float a = FLT_MAX, bsec = FLT_MAX;
                int   ka = 0x7FFFFFFF;
                #pragma unroll
                for (int q = 0; q < 4; ++q) {
                    float sc = (xs - 2.0f * c[q][r]) + es_q[q];
                    int   cd = (wave * 4 + q) * 16 + lo4;
                    if (sc < a) { bsec = a; a = sc; ka = cd; }
                    else        { bsec = fminf(bsec, sc); }
                }
                m1[r] = a; k1[r] = ka; m2[r] = bsec;
            }
            #pragma unroll
            for (int off = 1; off < 16; off <<= 1)
                #pragma unroll
                for (int r = 0; r < 4; ++r) {
                    float ov = __shfl_xor(m1[r], off, 64);
                    int   ok = __shfl_xor(k1[r], off, 64);
                    float o2 = __shfl_xor(m2[r], off, 64);
                    float n2 = fminf(fminf(m2[r], o2), fmaxf(m1[r], ov));
                    if (ov < m1[r] || (ov == m1[r] && ok < k1[r])) {
                        m1[r] = ov; k1[r] = ok;
                    }
                    m2[r] = n2;
                }
            if (lo4 == 0)
                #pragma unroll
                for (int r = 0; r < 4; ++r) {
                    int token = tb * 16 + hi4 * 4 + r;
                    redm1[wave][token] = m1[r];
                    redk1[wave][token] = k1[r];
                    redm2[wave][token] = m2[r];
                }
        }
        __syncthreads();                                         // B4

        // ---- combine 8 waves, wave-parallel (8 lanes per token) ----
        {
            int tk   = wave * 8 + (lane >> 3);
            int slot = lane & 7;
            float a    = redm1[slot][tk];
            float bsec = redm2[slot][tk];
            int   ka   = redk1[slot][tk];
            #pragma unroll
            for (int off = 1; off < 8; off <<= 1) {
                float ov = __shfl_xor(a, off, 64);
                int   ok = __shfl_xor(ka, off, 64);
                float o2 = __shfl_xor(bsec, off, 64);
                float n2 = fminf(fminf(bsec, o2), fmaxf(a, ov));
                if (ov < a || (ov == a && ok < ka)) { a = ov; ka = ok; }
                bsec = n2;
            }
            if (slot == 0) {
                if (bsec <= a + EPS) {           // near-tie -> exact recompute
                    int p = atomicAdd(&nflag_s, 1);
                    flag_s[p] = tk;
                } else {
                    bestk_s[tk] = ka;            // unique winner == np argmin
                }
            }
        }
        __syncthreads();                                         // B5

        // ---- exact pass: wave-parallel, no inner barriers. Lane owns codes
        //      8*lane..8*lane+7; d-ascending fmaf == verified np chain.
        {
            int nf = nflag_s;
            for (int f = wave; f < nf; f += 8) {
                int token = flag_s[f];
                float xs = xsq_s[token];
                float d0 = 0.f, d1 = 0.f, d2 = 0.f, d3 = 0.f;
                float d4 = 0.f, d5 = 0.f, d6 = 0.f, d7 = 0.f;
                const float* Ep = E + 8 * lane;
                #pragma unroll 4
                for (int d = 0; d < 64; ++d) {
                    float xv = xT[d][token];     // wave-uniform broadcast
                    float4 e0 = *reinterpret_cast<const float4*>(Ep + d * K_);
                    float4 e1 = *reinterpret_cast<const float4*>(Ep + d * K_ + 4);
                    d0 = fmaf(xv, e0.x, d0); d1 = fmaf(xv, e0.y, d1);
                    d2 = fmaf(xv, e0.z, d2); d3 = fmaf(xv, e0.w, d3);
                    d4 = fmaf(xv, e1.x, d4); d5 = fmaf(xv, e1.y, d5);
                    d6 = fmaf(xv, e1.z, d6); d7 = fmaf(xv, e1.w, d7);
                }
                float4 qa = *reinterpret_cast<const float4*>(&esq_s[8 * lane]);
                float4 qb = *reinterpret_cast<const float4*>(&esq_s[8 * lane + 4]);
                float sc[8];
                sc[0] = (xs - 2.0f * d0) + qa.x; sc[1] = (xs - 2.0f * d1) + qa.y;
                sc[2] = (xs - 2.0f * d2) + qa.z; sc[3] = (xs - 2.0f * d3) + qa.w;
                sc[4] = (xs - 2.0f * d4) + qb.x; sc[5] = (xs - 2.0f * d5) + qb.y;
                sc[6] = (xs - 2.0f * d6) + qb.z; sc[7] = (xs - 2.0f * d7) + qb.w;
                unsigned long long pk = ~0ULL;
                #pragma unroll
                for (int j = 0; j < 8; ++j) {    // ascending code: first-min kept
                    unsigned long long p =
                        ((unsigned long long)f32_sortable(sc[j]) << 32) |
                        (unsigned)(8 * lane + j);
                    if (p < pk) pk = p;
                }
                #pragma unroll
                for (int off = 1; off < 64; off <<= 1) {
                    unsigned long long o = __shfl_xor(pk, off, 64);
                    if (o < pk) pk = o;
                }
                if (lane == 0)
                    bestk_s[token] = (int)(unsigned)(pk & 0xFFFFFFFFULL);
            }
        }
        __syncthreads();                                         // B6

        // ---- epilogue: gather exact fp32 codebook rows + write ----
        {
            int qd = tid & 15, dg = tid >> 4;
            int i4 = qd * 4;
            int k0 = bestk_s[i4], kk1 = bestk_s[i4 + 1];
            int k2 = bestk_s[i4 + 2], k3 = bestk_s[i4 + 3];
            #pragma unroll
            for (int h = 0; h < 2; ++h) {
                int d = dg + h * 32;
                float4 v;
                v.x = E[d * K_ + k0];  v.y = E[d * K_ + kk1];
                v.z = E[d * K_ + k2];  v.w = E[d * K_ + k3];
                *reinterpret_cast<float4*>(out_emb + ((size_t)(b * 64 + d)) * L_ + l0 + i4) = v;
            }
        }
        if (tid < 64)
            out_idx[(size_t)b * L_ + l0 + tid] = (float)bestk_s[tid];
    }
}

extern "C" void kernel_launch(void* const* d_in, const int* in_sizes, int n_in,
                              void* d_out, int out_size, void* d_ws, size_t ws_size,
                              hipStream_t stream) {
    const float* X = (const float*)d_in[0];   // (B, D, L) fp32
    const float* E = (const float*)d_in[1];   // (D, K) fp32
    float* out     = (float*)d_out;
    float* out_emb = out;
    float* out_idx = out + (size_t)B_ * D_ * L_;
    vq_mfma_kernel<<<NBLOCKS, 512, 0, stream>>>(X, E, out_emb, out_idx);
}